// Round 3
// baseline (3866.943 us; speedup 1.0000x reference)
//
#include <hip/hip_runtime.h>

typedef __bf16 bf16;
typedef __bf16 bf16x4 __attribute__((ext_vector_type(4)));
typedef __bf16 bf16x8 __attribute__((ext_vector_type(8)));
typedef float  f32x4  __attribute__((ext_vector_type(4)));
typedef unsigned long long u64;

#define MFMA(a,b,c) __builtin_amdgcn_mfma_f32_16x16x32_bf16((a),(b),(c),0,0,0)

// Problem dims
#define TSTEPS 512
#define NBATCH 128
#define DIN    256
#define DH     1024
#define NRANK  128
#define DOUT   256

// Scan decomposition: 4 batch-pairs x 4 hidden-groups = 16 WGs.
// WG (p,g) owns batch rows [p*32,+32) as two phase-shifted halves A/B of 16,
// and h-cols [g*256,+256). Weights register-resident; IC latency hidden by
// interleaving the two independent halves.
#define NPAIR 4
#define NGH   4

// Workspace layout (bytes) — identical footprint to previous rounds.
#define ZI_OFF    0ull               // bf16 [512*128*1024]  = 134217728 B
#define QSEQ_OFF  134217728ull       // bf16 [512*128*128]   =  16777216 B
#define PBUF_OFF  150994944ull       // partials [2 par][2 half][4 p][4 g][16][128] bf16 = 262144 B
#define FLAG_OFF  (PBUF_OFF + 262144ull)   // 32 flags: [2 half][4 p][4 g]
#define WIN_OFF   151519232ull       // bf16 [1024*256]
#define U_OFF     152043520ull       // bf16 [128*1024]
#define V_OFF     152305664ull       // bf16 [1024*128]
#define WOUT_OFF  152567808ull       // bf16 [256*1024]
#define BAR_OFF   153092096ull       // legacy (unused)

// Coherent (agent-scope, cache-bypassing) 8-byte access helpers (proven pattern).
__device__ __forceinline__ void cstore64(u64* p, u64 v) {
  __hip_atomic_store(p, v, __ATOMIC_RELAXED, __HIP_MEMORY_SCOPE_AGENT);
}
__device__ __forceinline__ u64 cload64(const u64* p) {
  return __hip_atomic_load(p, __ATOMIC_RELAXED, __HIP_MEMORY_SCOPE_AGENT);
}
union B4U { u64 u; bf16x4 b; };

// ---------------------------------------------------------------- K0: prep (unchanged)
__global__ __launch_bounds__(256) void k_prep(const float* __restrict__ W_in,
                                              const float* __restrict__ U,
                                              const float* __restrict__ V,
                                              const float* __restrict__ W_out,
                                              char* __restrict__ ws) {
  bf16* winb  = (bf16*)(ws + WIN_OFF);
  bf16* ub    = (bf16*)(ws + U_OFF);
  bf16* vb    = (bf16*)(ws + V_OFF);
  bf16* woutb = (bf16*)(ws + WOUT_OFF);
  bf16* qseq  = (bf16*)(ws + QSEQ_OFF);
  unsigned* flg = (unsigned*)(ws + FLAG_OFF);
  size_t id = (size_t)blockIdx.x * 256 + threadIdx.x;
  if      (id < 262144) winb[id]           = (bf16)W_in[id];
  else if (id < 393216) ub[id - 262144]    = (bf16)U[id - 262144];
  else if (id < 524288) vb[id - 393216]    = (bf16)V[id - 393216];
  else if (id < 786432) woutb[id - 524288] = (bf16)W_out[id - 524288];
  else if (id < 802816) qseq[id - 786432]  = (bf16)0.0f;   // q_0 = 0
  else if (id < 802848) flg[id - 802816]   = 0u;           // 32 sync flags
}

// ---------------------------------------------------------------- K1: zi = x @ W_in^T  (unchanged)
__global__ __launch_bounds__(256) void k_zi(const float* __restrict__ x,
                                            const char* __restrict__ ws,
                                            bf16* __restrict__ zi) {
  const bf16* winb = (const bf16*)(ws + WIN_OFF);
  __shared__ bf16 xl[128 * 264];
  __shared__ bf16 wl[128 * 264];
  const int tid = threadIdx.x, lane = tid & 63, wv = tid >> 6;
  const int q4 = lane >> 4, l16 = lane & 15;
  const int m0b = blockIdx.x * 128, n0 = blockIdx.y * 128;

  for (int ch = tid; ch < 8192; ch += 256) {
    int r = ch >> 6, c4 = ch & 63;
    float4 f = *(const float4*)&x[(size_t)(m0b + r) * 256 + c4 * 4];
    bf16x4 b; b[0] = (bf16)f.x; b[1] = (bf16)f.y; b[2] = (bf16)f.z; b[3] = (bf16)f.w;
    *(bf16x4*)&xl[r * 264 + c4 * 4] = b;
  }
  for (int ch = tid; ch < 4096; ch += 256) {
    int r = ch >> 5, c8 = ch & 31;
    *(uint4*)&wl[r * 264 + c8 * 8] = *(const uint4*)&winb[(size_t)(n0 + r) * 256 + c8 * 8];
  }
  __syncthreads();

  f32x4 z4 = {0.f, 0.f, 0.f, 0.f};
  f32x4 acc[2][8];
#pragma unroll
  for (int i = 0; i < 2; i++)
#pragma unroll
    for (int j = 0; j < 8; j++) acc[i][j] = z4;

  const int m0 = wv * 32;
#pragma unroll
  for (int kc = 0; kc < 8; kc++) {
    bf16x8 a0 = *(bf16x8*)&xl[(m0 + l16) * 264 + kc * 32 + q4 * 8];
    bf16x8 a1 = *(bf16x8*)&xl[(m0 + 16 + l16) * 264 + kc * 32 + q4 * 8];
#pragma unroll
    for (int nt = 0; nt < 8; nt++) {
      bf16x8 b = *(bf16x8*)&wl[(nt * 16 + l16) * 264 + kc * 32 + q4 * 8];
      acc[0][nt] = MFMA(a0, b, acc[0][nt]);
      acc[1][nt] = MFMA(a1, b, acc[1][nt]);
    }
  }
  __syncthreads();
#pragma unroll
  for (int mt = 0; mt < 2; mt++)
#pragma unroll
    for (int nt = 0; nt < 8; nt++)
#pragma unroll
      for (int r = 0; r < 4; r++) {
        int m = m0 + mt * 16 + q4 * 4 + r;
        int c = nt * 16 + l16;
        xl[m * 136 + c] = (bf16)acc[mt][nt][r];
      }
  __syncthreads();
  for (int ch = tid; ch < 2048; ch += 256) {
    int r = ch >> 4, c8 = ch & 15;
    *(uint4*)&zi[(size_t)(m0b + r) * 1024 + n0 + c8 * 8] = *(uint4*)&xl[r * 136 + c8 * 8];
  }
}

// ---------------------------------------------------------------- K2: two-phase scan, register weights
__global__ __launch_bounds__(256, 1) void k_scan(char* __restrict__ ws,
                                                 const float* __restrict__ b_h) {
  const bf16* zi = (const bf16*)(ws + ZI_OFF);
  const bf16* ub = (const bf16*)(ws + U_OFF);
  const bf16* vb = (const bf16*)(ws + V_OFF);
  bf16* qseq = (bf16*)(ws + QSEQ_OFF);
  u64* pbufq = (u64*)(ws + PBUF_OFF);             // [2 par][2 half][4 p][4 g][512] u64
  unsigned* flag = (unsigned*)(ws + FLAG_OFF);    // [2 half][4 p][4 g]

  __shared__ bf16 qA[16 * 136], qB[16 * 136];   // q_t  [16 b][128 r]
  __shared__ bf16 hA[16 * 264], hB[16 * 264];   // h    [16 b][256 hcol]
  __shared__ bf16 psA[16 * 136], psB[16 * 136]; // partial staging
  // LDS total ~34 KB

  const int tid = threadIdx.x, lane = tid & 63, w = tid >> 6;   // 4 waves
  const int l16 = lane & 15, q4 = lane >> 4;
  const int p = blockIdx.x & 3, g = blockIdx.x >> 2;
  const int hcol0 = g * 256;
  const int rowA = p * 32, rowB = p * 32 + 16;

  // ---- weights -> registers (one-time). Same fragment geometry the LDS reads had.
  bf16x8 Vf[4][4];   // stage2 B: rows = hcol (w*64+nt*16+l16), k = rank (kc*32+q4*8)
  bf16x8 Uf[8][2];   // stage1 B: rows = rank (w*32+nt*16+l16), k = hcol (kc*32+q4*8)
#pragma unroll
  for (int kc = 0; kc < 4; kc++)
#pragma unroll
    for (int nt = 0; nt < 4; nt++)
      Vf[kc][nt] = *(const bf16x8*)&vb[(size_t)(hcol0 + w * 64 + nt * 16 + l16) * 128 + kc * 32 + q4 * 8];
#pragma unroll
  for (int kc = 0; kc < 8; kc++)
#pragma unroll
    for (int nt = 0; nt < 2; nt++)
      Uf[kc][nt] = *(const bf16x8*)&ub[(size_t)(w * 32 + nt * 16 + l16) * 1024 + hcol0 + kc * 32 + q4 * 8];

  float bj[4];
#pragma unroll
  for (int nt = 0; nt < 4; nt++) bj[nt] = b_h[hcol0 + w * 64 + nt * 16 + l16];

  for (int i = tid; i < 16 * 136; i += 256) { qA[i] = (bf16)0.0f; qB[i] = (bf16)0.0f; }

  bf16 zA[16], zB[16];   // zi at this thread's stage2 C-frag positions
#pragma unroll
  for (int nt = 0; nt < 4; nt++)
#pragma unroll
    for (int rr = 0; rr < 4; rr++) {
      int c = hcol0 + w * 64 + nt * 16 + l16;
      zA[nt * 4 + rr] = zi[(size_t)(rowA + q4 * 4 + rr) * 1024 + c];
      zB[nt * 4 + rr] = zi[(size_t)(rowB + q4 * 4 + rr) * 1024 + c];
    }
  __syncthreads();

  const f32x4 z4 = {0.f, 0.f, 0.f, 0.f};

  // COMP(X,t): consume qX(t), zX(t) -> h -> partial of q(t+1) -> publish + flag=t+1.
  auto COMP = [&](int t, int half, bf16* qX, bf16* hX, bf16* psX, bf16 (&zX)[16], int row0) {
    // stage2: zh[16][256-slice] = q @ V^T  (K=128)
    f32x4 az[4] = {z4, z4, z4, z4};
#pragma unroll
    for (int kc = 0; kc < 4; kc++) {
      bf16x8 a = *(const bf16x8*)&qX[l16 * 136 + kc * 32 + q4 * 8];
#pragma unroll
      for (int nt = 0; nt < 4; nt++) az[nt] = MFMA(a, Vf[kc][nt], az[nt]);
    }
#pragma unroll
    for (int nt = 0; nt < 4; nt++)
#pragma unroll
      for (int rr = 0; rr < 4; rr++) {
        float v = az[nt][rr] + bj[nt] + (float)zX[nt * 4 + rr];
        hX[(q4 * 4 + rr) * 264 + w * 64 + nt * 16 + l16] = (bf16)fmaxf(v, 0.0f);
      }
    __syncthreads();
    // prefetch zi(t+1) for this half (cached loads; complete under stage1)
#pragma unroll
    for (int nt = 0; nt < 4; nt++)
#pragma unroll
      for (int rr = 0; rr < 4; rr++)
        zX[nt * 4 + rr] =
            zi[((size_t)(t + 1) * NBATCH + row0 + q4 * 4 + rr) * 1024 + hcol0 + w * 64 + nt * 16 + l16];
    // stage1: partial[16][128] = h @ U^T  (K=256), 2x2 chains
    f32x4 ap0[2] = {z4, z4}, ap1[2] = {z4, z4};
#pragma unroll
    for (int kc = 0; kc < 8; kc += 2) {
      bf16x8 a0 = *(const bf16x8*)&hX[l16 * 264 + kc * 32 + q4 * 8];
      bf16x8 a1 = *(const bf16x8*)&hX[l16 * 264 + (kc + 1) * 32 + q4 * 8];
#pragma unroll
      for (int nt = 0; nt < 2; nt++) {
        ap0[nt] = MFMA(a0, Uf[kc][nt], ap0[nt]);
        ap1[nt] = MFMA(a1, Uf[kc + 1][nt], ap1[nt]);
      }
    }
#pragma unroll
    for (int nt = 0; nt < 2; nt++) {
      f32x4 s = ap0[nt] + ap1[nt];
#pragma unroll
      for (int rr = 0; rr < 4; rr++)
        psX[(q4 * 4 + rr) * 136 + w * 32 + nt * 16 + l16] = (bf16)s[rr];
    }
    __syncthreads();
    // publish partial (coherent), parity (t+1)&1
    u64* mybuf = &pbufq[(size_t)(((((t + 1) & 1) * 2 + half) * NPAIR + p) * NGH + g) * 512];
#pragma unroll
    for (int i = 0; i < 2; i++) {
      int e = tid + i * 256;
      cstore64(&mybuf[e], *(const u64*)&psX[(e >> 5) * 136 + (e & 31) * 4]);
    }
    __syncthreads();   // drains vmcnt for ALL waves -> partial at coherence point
    if (tid == 0)
      __hip_atomic_store(&flag[(half * NPAIR + p) * NGH + g], (unsigned)(t + 1),
                         __ATOMIC_RELEASE, __HIP_MEMORY_SCOPE_AGENT);
  };

  // PR(X,t): poll siblings' flags >= t, reduce 4 partials -> qX(t) (+ qseq by g==0).
  auto PR = [&](int t, int half, bf16* qX, bf16* psX, int row0) {
    if (tid < NGH) {
      while (__hip_atomic_load(&flag[(half * NPAIR + p) * NGH + tid],
                               __ATOMIC_RELAXED, __HIP_MEMORY_SCOPE_AGENT) < (unsigned)t) {}
    }
    __syncthreads();
    const u64* base = &pbufq[(size_t)(((t & 1) * 2 + half) * NPAIR + p) * NGH * 512];
#pragma unroll
    for (int i = 0; i < 2; i++) {
      int e = tid + i * 256;
      int r = e >> 5, c4 = e & 31;
      float s0 = 0.f, s1 = 0.f, s2 = 0.f, s3 = 0.f;
#pragma unroll
      for (int pp = 0; pp < NGH; pp++) {
        B4U v;
        if (pp == g) v.u = *(const u64*)&psX[r * 136 + c4 * 4];   // own partial from LDS
        else         v.u = cload64(&base[(size_t)pp * 512 + e]);
        s0 += (float)v.b[0]; s1 += (float)v.b[1]; s2 += (float)v.b[2]; s3 += (float)v.b[3];
      }
      B4U o; o.b[0] = (bf16)s0; o.b[1] = (bf16)s1; o.b[2] = (bf16)s2; o.b[3] = (bf16)s3;
      *(bf16x4*)&qX[r * 136 + c4 * 4] = o.b;
      if (g == 0)
        *(u64*)&qseq[((size_t)t * NBATCH + row0 + r) * NRANK + c4 * 4] = o.u;
    }
    __syncthreads();
  };

  // prologue: step 0 for both halves (q_0 = 0)
  COMP(0, 0, qA, hA, psA, zA, rowA);
  COMP(0, 1, qB, hB, psB, zB, rowB);

  for (int t = 1; t < TSTEPS; t++) {
    PR(t, 0, qA, psA, rowA);
    if (t < TSTEPS - 1) COMP(t, 0, qA, hA, psA, zA, rowA);
    PR(t, 1, qB, psB, rowB);
    if (t < TSTEPS - 1) COMP(t, 1, qB, hB, psB, zB, rowB);
  }
}

// ---------------------------------------------------------------- K3: hidden[t] = relu(q_t V^T + b + zi_t)  (unchanged)
__global__ __launch_bounds__(256) void k_hidden(const char* __restrict__ ws,
                                                const float* __restrict__ b_h,
                                                float* __restrict__ hid) {
  const bf16* qseq = (const bf16*)(ws + QSEQ_OFF);
  const bf16* vb   = (const bf16*)(ws + V_OFF);
  const bf16* zi   = (const bf16*)(ws + ZI_OFF);
  const int t = blockIdx.x, n0 = blockIdx.y * 128;
  const int tid = threadIdx.x, lane = tid & 63, wv = tid >> 6;
  const int q4 = lane >> 4, l16 = lane & 15;

  __shared__ bf16 ql2[128 * 136];
  __shared__ bf16 vl2[128 * 136];
  __shared__ bf16 zl2[128 * 136];
  __shared__ float bl2[128];

  for (int ch = tid; ch < 2048; ch += 256) {
    int r = ch >> 4, c8 = ch & 15;
    *(uint4*)&ql2[r * 136 + c8 * 8] = *(const uint4*)&qseq[(size_t)t * 16384 + r * 128 + c8 * 8];
    *(uint4*)&vl2[r * 136 + c8 * 8] = *(const uint4*)&vb[(size_t)(n0 + r) * 128 + c8 * 8];
    *(uint4*)&zl2[r * 136 + c8 * 8] = *(const uint4*)&zi[((size_t)t * 128 + r) * 1024 + n0 + c8 * 8];
  }
  if (tid < 128) bl2[tid] = b_h[n0 + tid];
  __syncthreads();

  f32x4 z4 = {0.f, 0.f, 0.f, 0.f};
  f32x4 acc[2][8];
#pragma unroll
  for (int i = 0; i < 2; i++)
#pragma unroll
    for (int j = 0; j < 8; j++) acc[i][j] = z4;

  const int m0 = wv * 32;
#pragma unroll
  for (int kc = 0; kc < 4; kc++) {
    bf16x8 a0 = *(bf16x8*)&ql2[(m0 + l16) * 136 + kc * 32 + q4 * 8];
    bf16x8 a1 = *(bf16x8*)&ql2[(m0 + 16 + l16) * 136 + kc * 32 + q4 * 8];
#pragma unroll
    for (int nt = 0; nt < 8; nt++) {
      bf16x8 b = *(bf16x8*)&vl2[(nt * 16 + l16) * 136 + kc * 32 + q4 * 8];
      acc[0][nt] = MFMA(a0, b, acc[0][nt]);
      acc[1][nt] = MFMA(a1, b, acc[1][nt]);
    }
  }
#pragma unroll
  for (int mt = 0; mt < 2; mt++)
#pragma unroll
    for (int nt = 0; nt < 8; nt++)
#pragma unroll
      for (int r = 0; r < 4; r++) {
        int m = m0 + mt * 16 + q4 * 4 + r;
        int c = nt * 16 + l16;
        float v = acc[mt][nt][r] + bl2[c] + (float)zl2[m * 136 + c];
        hid[((size_t)t * 128 + m) * 1024 + n0 + c] = fmaxf(v, 0.0f);
      }
}

// ---------------------------------------------------------------- K4: output = hidden @ W_out^T + b_out (unchanged)
__global__ __launch_bounds__(512) void k_out(const char* __restrict__ ws,
                                             const float* __restrict__ hid,
                                             const float* __restrict__ b_out,
                                             float* __restrict__ out) {
  const bf16* woutb = (const bf16*)(ws + WOUT_OFF);
  const int t = blockIdx.x;
  const int tid = threadIdx.x, lane = tid & 63, wv = tid >> 6;  // 8 waves
  const int q4 = lane >> 4, l16 = lane & 15;

  __shared__ bf16 hl2[128 * 136];
  __shared__ bf16 wl2[256 * 136];
  __shared__ float bol[256];
  if (tid < 256) bol[tid] = b_out[tid];

  f32x4 z4 = {0.f, 0.f, 0.f, 0.f};
  f32x4 acc[16];
#pragma unroll
  for (int j = 0; j < 16; j++) acc[j] = z4;

  const int m0 = wv * 16;
  for (int k0 = 0; k0 < 1024; k0 += 128) {
    __syncthreads();
    for (int ch = tid; ch < 4096; ch += 512) {
      int r = ch >> 5, c4 = ch & 31;
      float4 f = *(const float4*)&hid[((size_t)t * 128 + r) * 1024 + k0 + c4 * 4];
      bf16x4 b; b[0] = (bf16)f.x; b[1] = (bf16)f.y; b[2] = (bf16)f.z; b[3] = (bf16)f.w;
      *(bf16x4*)&hl2[r * 136 + c4 * 4] = b;
    }
    for (int ch = tid; ch < 4096; ch += 512) {
      int r = ch >> 4, c8 = ch & 15;
      *(uint4*)&wl2[r * 136 + c8 * 8] = *(const uint4*)&woutb[(size_t)r * 1024 + k0 + c8 * 8];
    }
    __syncthreads();
#pragma unroll
    for (int kc = 0; kc < 4; kc++) {
      bf16x8 a = *(bf16x8*)&hl2[(m0 + l16) * 136 + kc * 32 + q4 * 8];
#pragma unroll
      for (int nt = 0; nt < 16; nt++) {
        bf16x8 b = *(bf16x8*)&wl2[(nt * 16 + l16) * 136 + kc * 32 + q4 * 8];
        acc[nt] = MFMA(a, b, acc[nt]);
      }
    }
  }
#pragma unroll
  for (int nt = 0; nt < 16; nt++)
#pragma unroll
    for (int r = 0; r < 4; r++) {
      int m = m0 + q4 * 4 + r;
      int c = nt * 16 + l16;
      out[((size_t)t * 128 + m) * 256 + c] = acc[nt][r] + bol[c];
    }
}

// ---------------------------------------------------------------- launch
extern "C" void kernel_launch(void* const* d_in, const int* in_sizes, int n_in,
                              void* d_out, int out_size, void* d_ws, size_t ws_size,
                              hipStream_t stream) {
  (void)in_sizes; (void)n_in; (void)out_size; (void)ws_size;
  const float* x     = (const float*)d_in[0];
  const float* W_in  = (const float*)d_in[1];
  const float* U     = (const float*)d_in[2];
  const float* V     = (const float*)d_in[3];
  const float* b_h   = (const float*)d_in[4];
  const float* W_out = (const float*)d_in[5];
  const float* b_out = (const float*)d_in[6];
  char* ws = (char*)d_ws;
  float* hid = (float*)d_out;
  float* out = hid + (size_t)TSTEPS * NBATCH * DH;
  bf16* zi = (bf16*)(ws + ZI_OFF);

  k_prep<<<dim3(3137), dim3(256), 0, stream>>>(W_in, U, V, W_out, ws);
  k_zi<<<dim3(512, 8), dim3(256), 0, stream>>>(x, ws, zi);
  k_scan<<<dim3(NPAIR * NGH), dim3(256), 0, stream>>>(ws, b_h);
  k_hidden<<<dim3(512, 8), dim3(256), 0, stream>>>(ws, b_h, hid);
  k_out<<<dim3(512), dim3(512), 0, stream>>>(ws, hid, b_out, out);
}

// Round 4
// 3798.964 us; speedup vs baseline: 1.0179x; 1.0179x over previous
//
#include <hip/hip_runtime.h>

typedef __bf16 bf16;
typedef __bf16 bf16x4 __attribute__((ext_vector_type(4)));
typedef __bf16 bf16x8 __attribute__((ext_vector_type(8)));
typedef float  f32x4  __attribute__((ext_vector_type(4)));
typedef unsigned long long u64;
typedef unsigned int u32;

#define MFMA(a,b,c) __builtin_amdgcn_mfma_f32_16x16x32_bf16((a),(b),(c),0,0,0)

// Problem dims
#define TSTEPS 512
#define NBATCH 128
#define DIN    256
#define DH     1024
#define NRANK  128
#define DOUT   256

// Scan decomposition: 8 batch-groups x 4 hidden-groups = 32 WGs (round-2 proven).
#define NBG 8
#define NGH 4

// Workspace layout (bytes) — identical footprint to previous rounds.
#define ZI_OFF    0ull               // bf16 [512*128*1024]  = 134217728 B
#define QSEQ_OFF  134217728ull       // bf16 [512*128*128]   =  16777216 B
#define PBUF_OFF  150994944ull       // legacy (unused this round)
#define FLAG_OFF  (PBUF_OFF + 262144ull)
#define WIN_OFF   151519232ull       // bf16 [1024*256] = 524288 B; DEAD after k_zi ->
                                     // reused by k_scan as tag-packed partials
                                     // [2 par][8 bg][4 g][1024] u64 = 524288 B exactly.
#define U_OFF     152043520ull       // bf16 [128*1024]
#define V_OFF     152305664ull       // bf16 [1024*128]
#define WOUT_OFF  152567808ull       // bf16 [256*1024]
#define BAR_OFF   153092096ull       // legacy (unused)

// Coherent (agent-scope, cache-bypassing) 8-byte access helpers (proven pattern).
__device__ __forceinline__ void cstore64(u64* p, u64 v) {
  __hip_atomic_store(p, v, __ATOMIC_RELAXED, __HIP_MEMORY_SCOPE_AGENT);
}
__device__ __forceinline__ u64 cload64(const u64* p) {
  return __hip_atomic_load(p, __ATOMIC_RELAXED, __HIP_MEMORY_SCOPE_AGENT);
}

// Raw barrier: LDS-drain only; deliberately leaves VMEM (publish stores / zi
// prefetch) in flight. Rule #18: sched_barrier(0) fences around the asm waits.
#define BAR_LGKM() do { \
  asm volatile("s_waitcnt lgkmcnt(0)" ::: "memory"); \
  __builtin_amdgcn_sched_barrier(0); \
  __builtin_amdgcn_s_barrier(); \
  __builtin_amdgcn_sched_barrier(0); \
} while (0)

// ---------------------------------------------------------------- K0: prep (unchanged)
__global__ __launch_bounds__(256) void k_prep(const float* __restrict__ W_in,
                                              const float* __restrict__ U,
                                              const float* __restrict__ V,
                                              const float* __restrict__ W_out,
                                              char* __restrict__ ws) {
  bf16* winb  = (bf16*)(ws + WIN_OFF);
  bf16* ub    = (bf16*)(ws + U_OFF);
  bf16* vb    = (bf16*)(ws + V_OFF);
  bf16* woutb = (bf16*)(ws + WOUT_OFF);
  bf16* qseq  = (bf16*)(ws + QSEQ_OFF);
  unsigned* flg = (unsigned*)(ws + FLAG_OFF);
  size_t id = (size_t)blockIdx.x * 256 + threadIdx.x;
  if      (id < 262144) winb[id]           = (bf16)W_in[id];
  else if (id < 393216) ub[id - 262144]    = (bf16)U[id - 262144];
  else if (id < 524288) vb[id - 393216]    = (bf16)V[id - 393216];
  else if (id < 786432) woutb[id - 524288] = (bf16)W_out[id - 524288];
  else if (id < 802816) qseq[id - 786432]  = (bf16)0.0f;   // q_0 = 0
  else if (id < 802848) flg[id - 802816]   = 0u;           // legacy
}

// ---------------------------------------------------------------- K1: zi = x @ W_in^T  (unchanged)
__global__ __launch_bounds__(256) void k_zi(const float* __restrict__ x,
                                            const char* __restrict__ ws,
                                            bf16* __restrict__ zi) {
  const bf16* winb = (const bf16*)(ws + WIN_OFF);
  __shared__ bf16 xl[128 * 264];
  __shared__ bf16 wl[128 * 264];
  const int tid = threadIdx.x, lane = tid & 63, wv = tid >> 6;
  const int q4 = lane >> 4, l16 = lane & 15;
  const int m0b = blockIdx.x * 128, n0 = blockIdx.y * 128;

  for (int ch = tid; ch < 8192; ch += 256) {
    int r = ch >> 6, c4 = ch & 63;
    float4 f = *(const float4*)&x[(size_t)(m0b + r) * 256 + c4 * 4];
    bf16x4 b; b[0] = (bf16)f.x; b[1] = (bf16)f.y; b[2] = (bf16)f.z; b[3] = (bf16)f.w;
    *(bf16x4*)&xl[r * 264 + c4 * 4] = b;
  }
  for (int ch = tid; ch < 4096; ch += 256) {
    int r = ch >> 5, c8 = ch & 31;
    *(uint4*)&wl[r * 264 + c8 * 8] = *(const uint4*)&winb[(size_t)(n0 + r) * 256 + c8 * 8];
  }
  __syncthreads();

  f32x4 z4 = {0.f, 0.f, 0.f, 0.f};
  f32x4 acc[2][8];
#pragma unroll
  for (int i = 0; i < 2; i++)
#pragma unroll
    for (int j = 0; j < 8; j++) acc[i][j] = z4;

  const int m0 = wv * 32;
#pragma unroll
  for (int kc = 0; kc < 8; kc++) {
    bf16x8 a0 = *(bf16x8*)&xl[(m0 + l16) * 264 + kc * 32 + q4 * 8];
    bf16x8 a1 = *(bf16x8*)&xl[(m0 + 16 + l16) * 264 + kc * 32 + q4 * 8];
#pragma unroll
    for (int nt = 0; nt < 8; nt++) {
      bf16x8 b = *(bf16x8*)&wl[(nt * 16 + l16) * 264 + kc * 32 + q4 * 8];
      acc[0][nt] = MFMA(a0, b, acc[0][nt]);
      acc[1][nt] = MFMA(a1, b, acc[1][nt]);
    }
  }
  __syncthreads();
#pragma unroll
  for (int mt = 0; mt < 2; mt++)
#pragma unroll
    for (int nt = 0; nt < 8; nt++)
#pragma unroll
      for (int r = 0; r < 4; r++) {
        int m = m0 + mt * 16 + q4 * 4 + r;
        int c = nt * 16 + l16;
        xl[m * 136 + c] = (bf16)acc[mt][nt][r];
      }
  __syncthreads();
  for (int ch = tid; ch < 2048; ch += 256) {
    int r = ch >> 4, c8 = ch & 15;
    *(uint4*)&zi[(size_t)(m0b + r) * 1024 + n0 + c8 * 8] = *(uint4*)&xl[r * 136 + c8 * 8];
  }
}

// ---------------------------------------------------------------- K1b: clear tag-partials
// Runs after k_zi (W_in region dead) and before k_scan. Zero tags != any step tag.
__global__ __launch_bounds__(256) void k_clr(char* __restrict__ ws) {
  u64* tp = (u64*)(ws + WIN_OFF);
  tp[(size_t)blockIdx.x * 256 + threadIdx.x] = 0ull;   // 256 blocks -> 65536 u64 = 512 KB
}

// ---------------------------------------------------------------- K2: scan, flag-free tag protocol
// 32 WGs (bg,g): rows [bg*16,+16), h-cols [g*256,+256). Weights LDS-resident.
// Per step: stage2 (q->h) | barrier | stage1 transposed (U @ h^T -> partial in
// ACCUMULATORS, lane holds 4 consecutive ranks) | publish 4 tagged u64/thread
// (fire-and-forget, no drain, no flag) | reduce = tag-spin on the data itself |
// install q(t+1) | barrier.  2 barriers/step, 0 vmcnt drains.
__global__ __launch_bounds__(256) void k_scan(char* __restrict__ ws,
                                              const float* __restrict__ b_h) {
  const bf16* zi = (const bf16*)(ws + ZI_OFF);
  const bf16* ub = (const bf16*)(ws + U_OFF);
  const bf16* vb = (const bf16*)(ws + V_OFF);
  bf16* qseq = (bf16*)(ws + QSEQ_OFF);
  u64* tpb = (u64*)(ws + WIN_OFF);               // [2 par][8 bg][4 g][1024] u64

  __shared__ bf16 Vl[256 * 136];   // V[hcol0+r][rank]   69632 B
  __shared__ bf16 Ul[128 * 264];   // U[rank][hcol0+c]   67584 B
  __shared__ bf16 ql[16 * 136];    // q_t [row][rank]     4352 B
  __shared__ bf16 hl[16 * 264];    // h   [row][hcol]     8448 B
  // total 150016 B

  const int tid = threadIdx.x, lane = tid & 63, w = tid >> 6;   // 4 waves
  const int l16 = lane & 15, q4 = lane >> 4;
  const int bg = blockIdx.x & 7, g = blockIdx.x >> 3;
  const int brow0 = bg * 16, hcol0 = g * 256;

  // ---- stage weights (one-time, L2 -> LDS)
  for (int ch = tid; ch < 4096; ch += 256) {
    int r = ch >> 4, c8 = ch & 15;
    *(uint4*)&Vl[r * 136 + c8 * 8] = *(const uint4*)&vb[(size_t)(hcol0 + r) * 128 + c8 * 8];
  }
  for (int ch = tid; ch < 4096; ch += 256) {
    int r = ch >> 5, c8 = ch & 31;
    *(uint4*)&Ul[r * 264 + c8 * 8] = *(const uint4*)&ub[(size_t)r * 1024 + hcol0 + c8 * 8];
  }
  for (int i = tid; i < 16 * 136; i += 256) ql[i] = (bf16)0.0f;   // q_0 = 0

  float bj[4];
#pragma unroll
  for (int nt = 0; nt < 4; nt++) bj[nt] = b_h[hcol0 + w * 64 + nt * 16 + l16];

  // zi at this thread's stage2 C-frag positions
  bf16 zcur[16], znxt[16];
#pragma unroll
  for (int nt = 0; nt < 4; nt++)
#pragma unroll
    for (int rr = 0; rr < 4; rr++)
      zcur[nt * 4 + rr] = zi[(size_t)(brow0 + q4 * 4 + rr) * 1024 + hcol0 + w * 64 + nt * 16 + l16];
  __syncthreads();

  const f32x4 z4 = {0.f, 0.f, 0.f, 0.f};
  // reducer geometry: thread owns row = tid>>4, ranks [8*(tid&15), +8)
  const int rrow = tid >> 4, rk0 = (tid & 15) * 8;

  for (int t = 0; t < TSTEPS - 1; t++) {
    const u32 tg = (u32)(t + 1);
    const int par = (t + 1) & 1;

    // ---- prefetch zi[t+1]; latency hides under stage2+stage1+reduce (FIFO drain)
#pragma unroll
    for (int nt = 0; nt < 4; nt++)
#pragma unroll
      for (int rr = 0; rr < 4; rr++)
        znxt[nt * 4 + rr] =
            zi[((size_t)(t + 1) * NBATCH + brow0 + q4 * 4 + rr) * 1024 + hcol0 + w * 64 + nt * 16 + l16];

    // ---- stage2: zh[16][256-slice] = q_t @ V^T (K=128); h = relu(zh + b + zi_t)
    f32x4 az[4] = {z4, z4, z4, z4};
#pragma unroll
    for (int kc = 0; kc < 4; kc++) {
      bf16x8 a = *(const bf16x8*)&ql[l16 * 136 + kc * 32 + q4 * 8];
#pragma unroll
      for (int nt = 0; nt < 4; nt++) {
        bf16x8 bb = *(const bf16x8*)&Vl[(w * 64 + nt * 16 + l16) * 136 + kc * 32 + q4 * 8];
        az[nt] = MFMA(a, bb, az[nt]);
      }
    }
#pragma unroll
    for (int nt = 0; nt < 4; nt++)
#pragma unroll
      for (int rr = 0; rr < 4; rr++) {
        float v = az[nt][rr] + bj[nt] + (float)zcur[nt * 4 + rr];
        hl[(q4 * 4 + rr) * 264 + w * 64 + nt * 16 + l16] = (bf16)fmaxf(v, 0.0f);
      }
    BAR_LGKM();   // hl ready; ql fully consumed

    // ---- stage1 (TRANSPOSED): P[rank 128][batch 16] = U_slice @ h^T  (K=256)
    // A = U rows=rank (w*32+mt*16+l16), B = h rows=batch (l16).
    // C-frag: col(l16)=batch, rows = rank w*32+mt*16+q4*4+rr -> lane holds 4
    // CONSECUTIVE ranks of one batch row => direct tagged publish, no LDS staging.
    f32x4 ap[2] = {z4, z4};
#pragma unroll
    for (int kc = 0; kc < 8; kc++) {
      bf16x8 bh = *(const bf16x8*)&hl[l16 * 264 + kc * 32 + q4 * 8];
#pragma unroll
      for (int mt = 0; mt < 2; mt++) {
        bf16x8 au = *(const bf16x8*)&Ul[(w * 32 + mt * 16 + l16) * 264 + kc * 32 + q4 * 8];
        ap[mt] = MFMA(au, bh, ap[mt]);
      }
    }

    // ---- publish: u64 = [bf16 hi | bf16 lo | tag32], fire-and-forget
    u64* myp = &tpb[(size_t)((par * NBG + bg) * NGH + g) * 1024];
#pragma unroll
    for (int mt = 0; mt < 2; mt++) {
      u32 b0 = (u32)__builtin_bit_cast(unsigned short, (bf16)ap[mt][0]);
      u32 b1 = (u32)__builtin_bit_cast(unsigned short, (bf16)ap[mt][1]);
      u32 b2 = (u32)__builtin_bit_cast(unsigned short, (bf16)ap[mt][2]);
      u32 b3 = (u32)__builtin_bit_cast(unsigned short, (bf16)ap[mt][3]);
      int e0 = l16 * 64 + w * 16 + mt * 8 + q4 * 2;
      cstore64(&myp[e0],     ((u64)((b1 << 16) | b0) << 32) | tg);
      cstore64(&myp[e0 + 1], ((u64)((b3 << 16) | b2) << 32) | tg);
    }

    // ---- reduce: tag-spin on the 4 partials' data words (the loads ARE the poll)
    const u64* rb = &tpb[(size_t)(par * NBG + bg) * NGH * 1024];
    u64 vv[4][4];
#pragma unroll
    for (int p4 = 0; p4 < 4; p4++)
#pragma unroll
      for (int i = 0; i < 4; i++)
        vv[p4][i] = cload64(&rb[(size_t)p4 * 1024 + tid * 4 + i]);
#pragma unroll
    for (int p4 = 0; p4 < 4; p4++)
#pragma unroll
      for (int i = 0; i < 4; i++)
        while ((u32)vv[p4][i] != tg) vv[p4][i] = cload64(&rb[(size_t)p4 * 1024 + tid * 4 + i]);

    float s[8] = {0.f, 0.f, 0.f, 0.f, 0.f, 0.f, 0.f, 0.f};
#pragma unroll
    for (int p4 = 0; p4 < 4; p4++)
#pragma unroll
      for (int i = 0; i < 4; i++) {
        u32 hi = (u32)(vv[p4][i] >> 32);
        s[2 * i]     += __builtin_bit_cast(float, (hi & 0xFFFFu) << 16);
        s[2 * i + 1] += __builtin_bit_cast(float, (hi >> 16) << 16);
      }

    // ---- install q_{t+1} into ql (+ qseq by g==0)
    union { bf16x8 v; uint4 u; } qv;
#pragma unroll
    for (int k = 0; k < 8; k++) qv.v[k] = (bf16)s[k];
    *(bf16x8*)&ql[rrow * 136 + rk0] = qv.v;
    if (g == 0)
      *(uint4*)&qseq[((size_t)(t + 1) * NBATCH + brow0 + rrow) * NRANK + rk0] = qv.u;

    BAR_LGKM();   // ql ready for next stage2; hl free for overwrite

#pragma unroll
    for (int k = 0; k < 16; k++) zcur[k] = znxt[k];
  }
}

// ---------------------------------------------------------------- K3: hidden[t] = relu(q_t V^T + b + zi_t)  (unchanged)
__global__ __launch_bounds__(256) void k_hidden(const char* __restrict__ ws,
                                                const float* __restrict__ b_h,
                                                float* __restrict__ hid) {
  const bf16* qseq = (const bf16*)(ws + QSEQ_OFF);
  const bf16* vb   = (const bf16*)(ws + V_OFF);
  const bf16* zi   = (const bf16*)(ws + ZI_OFF);
  const int t = blockIdx.x, n0 = blockIdx.y * 128;
  const int tid = threadIdx.x, lane = tid & 63, wv = tid >> 6;
  const int q4 = lane >> 4, l16 = lane & 15;

  __shared__ bf16 ql2[128 * 136];
  __shared__ bf16 vl2[128 * 136];
  __shared__ bf16 zl2[128 * 136];
  __shared__ float bl2[128];

  for (int ch = tid; ch < 2048; ch += 256) {
    int r = ch >> 4, c8 = ch & 15;
    *(uint4*)&ql2[r * 136 + c8 * 8] = *(const uint4*)&qseq[(size_t)t * 16384 + r * 128 + c8 * 8];
    *(uint4*)&vl2[r * 136 + c8 * 8] = *(const uint4*)&vb[(size_t)(n0 + r) * 128 + c8 * 8];
    *(uint4*)&zl2[r * 136 + c8 * 8] = *(const uint4*)&zi[((size_t)t * 128 + r) * 1024 + n0 + c8 * 8];
  }
  if (tid < 128) bl2[tid] = b_h[n0 + tid];
  __syncthreads();

  f32x4 z4 = {0.f, 0.f, 0.f, 0.f};
  f32x4 acc[2][8];
#pragma unroll
  for (int i = 0; i < 2; i++)
#pragma unroll
    for (int j = 0; j < 8; j++) acc[i][j] = z4;

  const int m0 = wv * 32;
#pragma unroll
  for (int kc = 0; kc < 4; kc++) {
    bf16x8 a0 = *(bf16x8*)&ql2[(m0 + l16) * 136 + kc * 32 + q4 * 8];
    bf16x8 a1 = *(bf16x8*)&ql2[(m0 + 16 + l16) * 136 + kc * 32 + q4 * 8];
#pragma unroll
    for (int nt = 0; nt < 8; nt++) {
      bf16x8 b = *(bf16x8*)&vl2[(nt * 16 + l16) * 136 + kc * 32 + q4 * 8];
      acc[0][nt] = MFMA(a0, b, acc[0][nt]);
      acc[1][nt] = MFMA(a1, b, acc[1][nt]);
    }
  }
#pragma unroll
  for (int mt = 0; mt < 2; mt++)
#pragma unroll
    for (int nt = 0; nt < 8; nt++)
#pragma unroll
      for (int r = 0; r < 4; r++) {
        int m = m0 + mt * 16 + q4 * 4 + r;
        int c = nt * 16 + l16;
        float v = acc[mt][nt][r] + bl2[c] + (float)zl2[m * 136 + c];
        hid[((size_t)t * 128 + m) * 1024 + n0 + c] = fmaxf(v, 0.0f);
      }
}

// ---------------------------------------------------------------- K4: output = hidden @ W_out^T + b_out (unchanged)
__global__ __launch_bounds__(512) void k_out(const char* __restrict__ ws,
                                             const float* __restrict__ hid,
                                             const float* __restrict__ b_out,
                                             float* __restrict__ out) {
  const bf16* woutb = (const bf16*)(ws + WOUT_OFF);
  const int t = blockIdx.x;
  const int tid = threadIdx.x, lane = tid & 63, wv = tid >> 6;  // 8 waves
  const int q4 = lane >> 4, l16 = lane & 15;

  __shared__ bf16 hl2[128 * 136];
  __shared__ bf16 wl2[256 * 136];
  __shared__ float bol[256];
  if (tid < 256) bol[tid] = b_out[tid];

  f32x4 z4 = {0.f, 0.f, 0.f, 0.f};
  f32x4 acc[16];
#pragma unroll
  for (int j = 0; j < 16; j++) acc[j] = z4;

  const int m0 = wv * 16;
  for (int k0 = 0; k0 < 1024; k0 += 128) {
    __syncthreads();
    for (int ch = tid; ch < 4096; ch += 512) {
      int r = ch >> 5, c4 = ch & 31;
      float4 f = *(const float4*)&hid[((size_t)t * 128 + r) * 1024 + k0 + c4 * 4];
      bf16x4 b; b[0] = (bf16)f.x; b[1] = (bf16)f.y; b[2] = (bf16)f.z; b[3] = (bf16)f.w;
      *(bf16x4*)&hl2[r * 136 + c4 * 4] = b;
    }
    for (int ch = tid; ch < 4096; ch += 512) {
      int r = ch >> 4, c8 = ch & 15;
      *(uint4*)&wl2[r * 136 + c8 * 8] = *(const uint4*)&woutb[(size_t)r * 1024 + k0 + c8 * 8];
    }
    __syncthreads();
#pragma unroll
    for (int kc = 0; kc < 4; kc++) {
      bf16x8 a = *(bf16x8*)&hl2[(m0 + l16) * 136 + kc * 32 + q4 * 8];
#pragma unroll
      for (int nt = 0; nt < 16; nt++) {
        bf16x8 b = *(bf16x8*)&wl2[(nt * 16 + l16) * 136 + kc * 32 + q4 * 8];
        acc[nt] = MFMA(a, b, acc[nt]);
      }
    }
  }
#pragma unroll
  for (int nt = 0; nt < 16; nt++)
#pragma unroll
    for (int r = 0; r < 4; r++) {
      int m = m0 + q4 * 4 + r;
      int c = nt * 16 + l16;
      out[((size_t)t * 128 + m) * 256 + c] = acc[nt][r] + bol[c];
    }
}

// ---------------------------------------------------------------- launch
extern "C" void kernel_launch(void* const* d_in, const int* in_sizes, int n_in,
                              void* d_out, int out_size, void* d_ws, size_t ws_size,
                              hipStream_t stream) {
  (void)in_sizes; (void)n_in; (void)out_size; (void)ws_size;
  const float* x     = (const float*)d_in[0];
  const float* W_in  = (const float*)d_in[1];
  const float* U     = (const float*)d_in[2];
  const float* V     = (const float*)d_in[3];
  const float* b_h   = (const float*)d_in[4];
  const float* W_out = (const float*)d_in[5];
  const float* b_out = (const float*)d_in[6];
  char* ws = (char*)d_ws;
  float* hid = (float*)d_out;
  float* out = hid + (size_t)TSTEPS * NBATCH * DH;
  bf16* zi = (bf16*)(ws + ZI_OFF);

  k_prep<<<dim3(3137), dim3(256), 0, stream>>>(W_in, U, V, W_out, ws);
  k_zi<<<dim3(512, 8), dim3(256), 0, stream>>>(x, ws, zi);
  k_clr<<<dim3(256), dim3(256), 0, stream>>>(ws);
  k_scan<<<dim3(NBG * NGH), dim3(256), 0, stream>>>(ws, b_h);
  k_hidden<<<dim3(512, 8), dim3(256), 0, stream>>>(ws, b_h, hid);
  k_out<<<dim3(512), dim3(512), 0, stream>>>(ws, hid, b_out, out);
}

// Round 5
// 3471.081 us; speedup vs baseline: 1.1140x; 1.0945x over previous
//
#include <hip/hip_runtime.h>

typedef __bf16 bf16;
typedef __bf16 bf16x4 __attribute__((ext_vector_type(4)));
typedef __bf16 bf16x8 __attribute__((ext_vector_type(8)));
typedef float  f32x4  __attribute__((ext_vector_type(4)));
typedef unsigned long long u64;
typedef unsigned int u32;

#define MFMA(a,b,c) __builtin_amdgcn_mfma_f32_16x16x32_bf16((a),(b),(c),0,0,0)

// Problem dims
#define TSTEPS 512
#define NBATCH 128
#define DIN    256
#define DH     1024
#define NRANK  128
#define DOUT   256

// Scan decomposition: 4 batch-pairs x 4 hidden-groups = 16 WGs.
// WG (p,g): batch rows [p*32,+32) as two phase-shifted halves A/B of 16 rows,
// h-cols [g*256,+256). Weights LDS-resident (round-2 proven). IC round trips
// of one half hidden under the other half's compute (round-3 idea, now with
// LDS weights). Stage1 transposed -> publish directly from accumulators
// (round-4 verified geometry), which frees the LDS needed to fit everything.
#define NPAIR 4
#define NGH   4

// Workspace layout (bytes) — identical footprint to previous rounds.
#define ZI_OFF    0ull               // bf16 [512*128*1024]  = 134217728 B
#define QSEQ_OFF  134217728ull       // bf16 [512*128*128]   =  16777216 B
#define PBUF_OFF  150994944ull       // partials [2 par][2 half][4 p][4 g][512] u64 = 262144 B
#define FLAG_OFF  (PBUF_OFF + 262144ull)   // 32 flags: [2 half][4 p][4 g]
#define WIN_OFF   151519232ull       // bf16 [1024*256]
#define U_OFF     152043520ull       // bf16 [128*1024]
#define V_OFF     152305664ull       // bf16 [1024*128]
#define WOUT_OFF  152567808ull       // bf16 [256*1024]
#define BAR_OFF   153092096ull       // legacy (unused)

// Coherent (agent-scope, cache-bypassing) 8-byte access helpers (proven pattern).
__device__ __forceinline__ void cstore64(u64* p, u64 v) {
  __hip_atomic_store(p, v, __ATOMIC_RELAXED, __HIP_MEMORY_SCOPE_AGENT);
}
__device__ __forceinline__ u64 cload64(const u64* p) {
  return __hip_atomic_load(p, __ATOMIC_RELAXED, __HIP_MEMORY_SCOPE_AGENT);
}
__device__ __forceinline__ float bfbits(u32 hs) {
  return __builtin_bit_cast(float, hs << 16);
}

// LDS-only barrier: leaves VMEM (publish stores / zi prefetch) in flight.
#define BAR_LGKM() do { \
  asm volatile("s_waitcnt lgkmcnt(0)" ::: "memory"); \
  __builtin_amdgcn_sched_barrier(0); \
  __builtin_amdgcn_s_barrier(); \
  __builtin_amdgcn_sched_barrier(0); \
} while (0)

// ---------------------------------------------------------------- K0: prep (unchanged)
__global__ __launch_bounds__(256) void k_prep(const float* __restrict__ W_in,
                                              const float* __restrict__ U,
                                              const float* __restrict__ V,
                                              const float* __restrict__ W_out,
                                              char* __restrict__ ws) {
  bf16* winb  = (bf16*)(ws + WIN_OFF);
  bf16* ub    = (bf16*)(ws + U_OFF);
  bf16* vb    = (bf16*)(ws + V_OFF);
  bf16* woutb = (bf16*)(ws + WOUT_OFF);
  bf16* qseq  = (bf16*)(ws + QSEQ_OFF);
  unsigned* flg = (unsigned*)(ws + FLAG_OFF);
  size_t id = (size_t)blockIdx.x * 256 + threadIdx.x;
  if      (id < 262144) winb[id]           = (bf16)W_in[id];
  else if (id < 393216) ub[id - 262144]    = (bf16)U[id - 262144];
  else if (id < 524288) vb[id - 393216]    = (bf16)V[id - 393216];
  else if (id < 786432) woutb[id - 524288] = (bf16)W_out[id - 524288];
  else if (id < 802816) qseq[id - 786432]  = (bf16)0.0f;   // q_0 = 0
  else if (id < 802848) flg[id - 802816]   = 0u;           // 32 sync flags (reset every launch)
}

// ---------------------------------------------------------------- K1: zi = x @ W_in^T  (unchanged)
__global__ __launch_bounds__(256) void k_zi(const float* __restrict__ x,
                                            const char* __restrict__ ws,
                                            bf16* __restrict__ zi) {
  const bf16* winb = (const bf16*)(ws + WIN_OFF);
  __shared__ bf16 xl[128 * 264];
  __shared__ bf16 wl[128 * 264];
  const int tid = threadIdx.x, lane = tid & 63, wv = tid >> 6;
  const int q4 = lane >> 4, l16 = lane & 15;
  const int m0b = blockIdx.x * 128, n0 = blockIdx.y * 128;

  for (int ch = tid; ch < 8192; ch += 256) {
    int r = ch >> 6, c4 = ch & 63;
    float4 f = *(const float4*)&x[(size_t)(m0b + r) * 256 + c4 * 4];
    bf16x4 b; b[0] = (bf16)f.x; b[1] = (bf16)f.y; b[2] = (bf16)f.z; b[3] = (bf16)f.w;
    *(bf16x4*)&xl[r * 264 + c4 * 4] = b;
  }
  for (int ch = tid; ch < 4096; ch += 256) {
    int r = ch >> 5, c8 = ch & 31;
    *(uint4*)&wl[r * 264 + c8 * 8] = *(const uint4*)&winb[(size_t)(n0 + r) * 256 + c8 * 8];
  }
  __syncthreads();

  f32x4 z4 = {0.f, 0.f, 0.f, 0.f};
  f32x4 acc[2][8];
#pragma unroll
  for (int i = 0; i < 2; i++)
#pragma unroll
    for (int j = 0; j < 8; j++) acc[i][j] = z4;

  const int m0 = wv * 32;
#pragma unroll
  for (int kc = 0; kc < 8; kc++) {
    bf16x8 a0 = *(bf16x8*)&xl[(m0 + l16) * 264 + kc * 32 + q4 * 8];
    bf16x8 a1 = *(bf16x8*)&xl[(m0 + 16 + l16) * 264 + kc * 32 + q4 * 8];
#pragma unroll
    for (int nt = 0; nt < 8; nt++) {
      bf16x8 b = *(bf16x8*)&wl[(nt * 16 + l16) * 264 + kc * 32 + q4 * 8];
      acc[0][nt] = MFMA(a0, b, acc[0][nt]);
      acc[1][nt] = MFMA(a1, b, acc[1][nt]);
    }
  }
  __syncthreads();
#pragma unroll
  for (int mt = 0; mt < 2; mt++)
#pragma unroll
    for (int nt = 0; nt < 8; nt++)
#pragma unroll
      for (int r = 0; r < 4; r++) {
        int m = m0 + mt * 16 + q4 * 4 + r;
        int c = nt * 16 + l16;
        xl[m * 136 + c] = (bf16)acc[mt][nt][r];
      }
  __syncthreads();
  for (int ch = tid; ch < 2048; ch += 256) {
    int r = ch >> 4, c8 = ch & 15;
    *(uint4*)&zi[(size_t)(m0b + r) * 1024 + n0 + c8 * 8] = *(uint4*)&xl[r * 136 + c8 * 8];
  }
}

// ---------------------------------------------------------------- K2: two-phase scan, LDS weights
__global__ __launch_bounds__(256, 1) void k_scan(char* __restrict__ ws,
                                                 const float* __restrict__ b_h) {
  const bf16* zi = (const bf16*)(ws + ZI_OFF);
  const bf16* ub = (const bf16*)(ws + U_OFF);
  const bf16* vb = (const bf16*)(ws + V_OFF);
  bf16* qseq = (bf16*)(ws + QSEQ_OFF);
  u64* pbuf = (u64*)(ws + PBUF_OFF);              // [2 par][2 half][4 p][4 g][512] u64
  unsigned* flag = (unsigned*)(ws + FLAG_OFF);    // [2 half][4 p][4 g]

  __shared__ bf16 Vl[256 * 136];   // V[hcol0+r][rank]   69632 B
  __shared__ bf16 Ul[128 * 264];   // U[rank][hcol0+c]   67584 B
  __shared__ bf16 qA[16 * 136], qB[16 * 136];   //  8704 B
  __shared__ bf16 hA[16 * 264], hB[16 * 264];   // 16896 B
  // total 162816 B <= 163840

  const int tid = threadIdx.x, lane = tid & 63, w = tid >> 6;   // 4 waves
  const int l16 = lane & 15, q4 = lane >> 4;
  const int p = blockIdx.x & 3, g = blockIdx.x >> 2;
  const int hcol0 = g * 256;
  const int rowA = p * 32, rowB = p * 32 + 16;

  // ---- stage weights (one-time, L2 -> LDS)
  for (int ch = tid; ch < 4096; ch += 256) {
    int r = ch >> 4, c8 = ch & 15;
    *(uint4*)&Vl[r * 136 + c8 * 8] = *(const uint4*)&vb[(size_t)(hcol0 + r) * 128 + c8 * 8];
  }
  for (int ch = tid; ch < 4096; ch += 256) {
    int r = ch >> 5, c8 = ch & 31;
    *(uint4*)&Ul[r * 264 + c8 * 8] = *(const uint4*)&ub[(size_t)r * 1024 + hcol0 + c8 * 8];
  }
  for (int i = tid; i < 16 * 136; i += 256) { qA[i] = (bf16)0.0f; qB[i] = (bf16)0.0f; }

  float bj[4];
#pragma unroll
  for (int nt = 0; nt < 4; nt++) bj[nt] = b_h[hcol0 + w * 64 + nt * 16 + l16];

  bf16 zA[16], znA[16], zB[16], znB[16];
#pragma unroll
  for (int nt = 0; nt < 4; nt++)
#pragma unroll
    for (int rr = 0; rr < 4; rr++) {
      int c = hcol0 + w * 64 + nt * 16 + l16;
      zA[nt * 4 + rr] = zi[(size_t)(rowA + q4 * 4 + rr) * 1024 + c];
      zB[nt * 4 + rr] = zi[(size_t)(rowB + q4 * 4 + rr) * 1024 + c];
    }
  __syncthreads();

  const f32x4 z4 = {0.f, 0.f, 0.f, 0.f};

  // STAGES(X,t): stage2 (q->h) | BAR_LGKM | stage1 transposed (U @ h^T) ->
  // publish directly from accumulators (fire-and-forget; drained by the NEXT
  // full __syncthreads, which is where flagX(t+1) gets released).
  auto STAGES = [&](bf16* qX, bf16* hX, bf16 (&zc)[16], bf16 (&zn)[16],
                    int row0, int half, int t) {
    const int tn = t + 1;
    // prefetch zi[t+1] (cached; zi is L3-resident; drains at next full sync)
#pragma unroll
    for (int nt = 0; nt < 4; nt++)
#pragma unroll
      for (int rr = 0; rr < 4; rr++)
        zn[nt * 4 + rr] =
            zi[((size_t)tn * NBATCH + row0 + q4 * 4 + rr) * 1024 + hcol0 + w * 64 + nt * 16 + l16];
    // stage2: zh[16][256-slice] = q @ V^T (K=128); h = relu(zh + b + zi)
    f32x4 az[4] = {z4, z4, z4, z4};
#pragma unroll
    for (int kc = 0; kc < 4; kc++) {
      bf16x8 a = *(const bf16x8*)&qX[l16 * 136 + kc * 32 + q4 * 8];
#pragma unroll
      for (int nt = 0; nt < 4; nt++) {
        bf16x8 bb = *(const bf16x8*)&Vl[(w * 64 + nt * 16 + l16) * 136 + kc * 32 + q4 * 8];
        az[nt] = MFMA(a, bb, az[nt]);
      }
    }
#pragma unroll
    for (int nt = 0; nt < 4; nt++)
#pragma unroll
      for (int rr = 0; rr < 4; rr++) {
        float v = az[nt][rr] + bj[nt] + (float)zc[nt * 4 + rr];
        hX[(q4 * 4 + rr) * 264 + w * 64 + nt * 16 + l16] = (bf16)fmaxf(v, 0.0f);
      }
    BAR_LGKM();   // hX ready (LDS only; VMEM stays in flight)
    // stage1 (transposed, round-4 verified): P[rank][batch] = U_slice @ h^T, K=256
    f32x4 ap[2] = {z4, z4};
#pragma unroll
    for (int kc = 0; kc < 8; kc++) {
      bf16x8 bh = *(const bf16x8*)&hX[l16 * 264 + kc * 32 + q4 * 8];
#pragma unroll
      for (int mt = 0; mt < 2; mt++) {
        bf16x8 au = *(const bf16x8*)&Ul[(w * 32 + mt * 16 + l16) * 264 + kc * 32 + q4 * 8];
        ap[mt] = MFMA(au, bh, ap[mt]);
      }
    }
    // publish: lane holds ranks w*32+mt*16+q4*4+rr for batch col l16 ->
    // u64 at [batch l16][rank/4] in a [16][128] bf16 row-major buffer.
    u64* myp = &pbuf[(size_t)((((tn & 1) * 2 + half) * NPAIR + p) * NGH + g) * 512];
#pragma unroll
    for (int mt = 0; mt < 2; mt++) {
      union { bf16x4 b; u64 u; } pk;
      pk.b[0] = (bf16)ap[mt][0]; pk.b[1] = (bf16)ap[mt][1];
      pk.b[2] = (bf16)ap[mt][2]; pk.b[3] = (bf16)ap[mt][3];
      cstore64(&myp[l16 * 32 + w * 8 + mt * 4 + q4], pk.u);
    }
#pragma unroll
    for (int k = 0; k < 16; k++) zc[k] = zn[k];
  };

  // REDUCE(X,t): sum 4 sibling partials -> qX (LDS) + qseq (g==0).
  // Thread owns batch row tid>>4, ranks [(tid&15)*8, +8): loads = 2 u64/partial,
  // fully coalesced (tid*2 contiguous across the WG).
  auto REDUCE = [&](bf16* qX, int row0, int half, int t) {
    const u64* rb = &pbuf[(size_t)(((t & 1) * 2 + half) * NPAIR + p) * NGH * 512];
    u64 vv[8];
#pragma unroll
    for (int pp = 0; pp < 4; pp++) {
      vv[pp * 2]     = cload64(&rb[(size_t)pp * 512 + tid * 2]);
      vv[pp * 2 + 1] = cload64(&rb[(size_t)pp * 512 + tid * 2 + 1]);
    }
    float s[8] = {0.f, 0.f, 0.f, 0.f, 0.f, 0.f, 0.f, 0.f};
#pragma unroll
    for (int pp = 0; pp < 4; pp++)
#pragma unroll
      for (int i = 0; i < 2; i++) {
        u64 u = vv[pp * 2 + i];
        s[i * 4 + 0] += bfbits((u32)(u & 0xFFFFu));
        s[i * 4 + 1] += bfbits((u32)((u >> 16) & 0xFFFFu));
        s[i * 4 + 2] += bfbits((u32)((u >> 32) & 0xFFFFu));
        s[i * 4 + 3] += bfbits((u32)(u >> 48));
      }
    union { bf16x8 v; uint4 u4; } qv;
#pragma unroll
    for (int k = 0; k < 8; k++) qv.v[k] = (bf16)s[k];
    *(bf16x8*)&qX[(tid >> 4) * 136 + (tid & 15) * 8] = qv.v;
    if (g == 0)
      *(uint4*)&qseq[((size_t)t * NBATCH + row0 + (tid >> 4)) * NRANK + (tid & 15) * 8] = qv.u4;
  };

  const int fA = 0 * 16 + p * 4, fB = 1 * 16 + p * 4;   // flag base per half

  // ---- prologue: t=0 (q_0 = 0)
  STAGES(qA, hA, zA, znA, rowA, 0, 0);
  __syncthreads();                                   // drains A(1) publishes
  if (tid == 0)
    __hip_atomic_store(&flag[fA + g], 1u, __ATOMIC_RELEASE, __HIP_MEMORY_SCOPE_AGENT);
  STAGES(qB, hB, zB, znB, rowB, 1, 0);

  for (int t = 1; t <= TSTEPS - 1; t++) {
    // ---- A phase ----
    if (tid < NGH) {
      while (__hip_atomic_load(&flag[fA + tid], __ATOMIC_RELAXED, __HIP_MEMORY_SCOPE_AGENT) <
             (unsigned)t) {}
    }
    __syncthreads();                                 // poll done; drains B(t) publishes
    if (tid == 0)
      __hip_atomic_store(&flag[fB + g], (unsigned)t, __ATOMIC_RELEASE, __HIP_MEMORY_SCOPE_AGENT);
    REDUCE(qA, rowA, 0, t);
    BAR_LGKM();                                      // qA ready
    if (t < TSTEPS - 1) STAGES(qA, hA, zA, znA, rowA, 0, t);
    // ---- B phase ----
    if (tid < NGH) {
      while (__hip_atomic_load(&flag[fB + tid], __ATOMIC_RELAXED, __HIP_MEMORY_SCOPE_AGENT) <
             (unsigned)t) {}
    }
    __syncthreads();                                 // drains A(t+1) publishes
    if (t < TSTEPS - 1 && tid == 0)
      __hip_atomic_store(&flag[fA + g], (unsigned)(t + 1), __ATOMIC_RELEASE, __HIP_MEMORY_SCOPE_AGENT);
    REDUCE(qB, rowB, 1, t);
    BAR_LGKM();                                      // qB ready
    if (t < TSTEPS - 1) STAGES(qB, hB, zB, znB, rowB, 1, t);
    // flagB(t+1) released at next iteration's A-phase sync.
  }
}

// ---------------------------------------------------------------- K3: hidden[t] = relu(q_t V^T + b + zi_t)  (unchanged)
__global__ __launch_bounds__(256) void k_hidden(const char* __restrict__ ws,
                                                const float* __restrict__ b_h,
                                                float* __restrict__ hid) {
  const bf16* qseq = (const bf16*)(ws + QSEQ_OFF);
  const bf16* vb   = (const bf16*)(ws + V_OFF);
  const bf16* zi   = (const bf16*)(ws + ZI_OFF);
  const int t = blockIdx.x, n0 = blockIdx.y * 128;
  const int tid = threadIdx.x, lane = tid & 63, wv = tid >> 6;
  const int q4 = lane >> 4, l16 = lane & 15;

  __shared__ bf16 ql2[128 * 136];
  __shared__ bf16 vl2[128 * 136];
  __shared__ bf16 zl2[128 * 136];
  __shared__ float bl2[128];

  for (int ch = tid; ch < 2048; ch += 256) {
    int r = ch >> 4, c8 = ch & 15;
    *(uint4*)&ql2[r * 136 + c8 * 8] = *(const uint4*)&qseq[(size_t)t * 16384 + r * 128 + c8 * 8];
    *(uint4*)&vl2[r * 136 + c8 * 8] = *(const uint4*)&vb[(size_t)(n0 + r) * 128 + c8 * 8];
    *(uint4*)&zl2[r * 136 + c8 * 8] = *(const uint4*)&zi[((size_t)t * 128 + r) * 1024 + n0 + c8 * 8];
  }
  if (tid < 128) bl2[tid] = b_h[n0 + tid];
  __syncthreads();

  f32x4 z4 = {0.f, 0.f, 0.f, 0.f};
  f32x4 acc[2][8];
#pragma unroll
  for (int i = 0; i < 2; i++)
#pragma unroll
    for (int j = 0; j < 8; j++) acc[i][j] = z4;

  const int m0 = wv * 32;
#pragma unroll
  for (int kc = 0; kc < 4; kc++) {
    bf16x8 a0 = *(bf16x8*)&ql2[(m0 + l16) * 136 + kc * 32 + q4 * 8];
    bf16x8 a1 = *(bf16x8*)&ql2[(m0 + 16 + l16) * 136 + kc * 32 + q4 * 8];
#pragma unroll
    for (int nt = 0; nt < 8; nt++) {
      bf16x8 b = *(bf16x8*)&vl2[(nt * 16 + l16) * 136 + kc * 32 + q4 * 8];
      acc[0][nt] = MFMA(a0, b, acc[0][nt]);
      acc[1][nt] = MFMA(a1, b, acc[1][nt]);
    }
  }
#pragma unroll
  for (int mt = 0; mt < 2; mt++)
#pragma unroll
    for (int nt = 0; nt < 8; nt++)
#pragma unroll
      for (int r = 0; r < 4; r++) {
        int m = m0 + mt * 16 + q4 * 4 + r;
        int c = nt * 16 + l16;
        float v = acc[mt][nt][r] + bl2[c] + (float)zl2[m * 136 + c];
        hid[((size_t)t * 128 + m) * 1024 + n0 + c] = fmaxf(v, 0.0f);
      }
}

// ---------------------------------------------------------------- K4: output = hidden @ W_out^T + b_out (unchanged)
__global__ __launch_bounds__(512) void k_out(const char* __restrict__ ws,
                                             const float* __restrict__ hid,
                                             const float* __restrict__ b_out,
                                             float* __restrict__ out) {
  const bf16* woutb = (const bf16*)(ws + WOUT_OFF);
  const int t = blockIdx.x;
  const int tid = threadIdx.x, lane = tid & 63, wv = tid >> 6;  // 8 waves
  const int q4 = lane >> 4, l16 = lane & 15;

  __shared__ bf16 hl2[128 * 136];
  __shared__ bf16 wl2[256 * 136];
  __shared__ float bol[256];
  if (tid < 256) bol[tid] = b_out[tid];

  f32x4 z4 = {0.f, 0.f, 0.f, 0.f};
  f32x4 acc[16];
#pragma unroll
  for (int j = 0; j < 16; j++) acc[j] = z4;

  const int m0 = wv * 16;
  for (int k0 = 0; k0 < 1024; k0 += 128) {
    __syncthreads();
    for (int ch = tid; ch < 4096; ch += 512) {
      int r = ch >> 5, c4 = ch & 31;
      float4 f = *(const float4*)&hid[((size_t)t * 128 + r) * 1024 + k0 + c4 * 4];
      bf16x4 b; b[0] = (bf16)f.x; b[1] = (bf16)f.y; b[2] = (bf16)f.z; b[3] = (bf16)f.w;
      *(bf16x4*)&hl2[r * 136 + c4 * 4] = b;
    }
    for (int ch = tid; ch < 4096; ch += 512) {
      int r = ch >> 4, c8 = ch & 15;
      *(uint4*)&wl2[r * 136 + c8 * 8] = *(const uint4*)&woutb[(size_t)r * 1024 + k0 + c8 * 8];
    }
    __syncthreads();
#pragma unroll
    for (int kc = 0; kc < 4; kc++) {
      bf16x8 a = *(bf16x8*)&hl2[(m0 + l16) * 136 + kc * 32 + q4 * 8];
#pragma unroll
      for (int nt = 0; nt < 16; nt++) {
        bf16x8 b = *(bf16x8*)&wl2[(nt * 16 + l16) * 136 + kc * 32 + q4 * 8];
        acc[nt] = MFMA(a, b, acc[nt]);
      }
    }
  }
#pragma unroll
  for (int nt = 0; nt < 16; nt++)
#pragma unroll
    for (int r = 0; r < 4; r++) {
      int m = m0 + q4 * 4 + r;
      int c = nt * 16 + l16;
      out[((size_t)t * 128 + m) * 256 + c] = acc[nt][r] + bol[c];
    }
}

// ---------------------------------------------------------------- launch
extern "C" void kernel_launch(void* const* d_in, const int* in_sizes, int n_in,
                              void* d_out, int out_size, void* d_ws, size_t ws_size,
                              hipStream_t stream) {
  (void)in_sizes; (void)n_in; (void)out_size; (void)ws_size;
  const float* x     = (const float*)d_in[0];
  const float* W_in  = (const float*)d_in[1];
  const float* U     = (const float*)d_in[2];
  const float* V     = (const float*)d_in[3];
  const float* b_h   = (const float*)d_in[4];
  const float* W_out = (const float*)d_in[5];
  const float* b_out = (const float*)d_in[6];
  char* ws = (char*)d_ws;
  float* hid = (float*)d_out;
  float* out = hid + (size_t)TSTEPS * NBATCH * DH;
  bf16* zi = (bf16*)(ws + ZI_OFF);

  k_prep<<<dim3(3137), dim3(256), 0, stream>>>(W_in, U, V, W_out, ws);
  k_zi<<<dim3(512, 8), dim3(256), 0, stream>>>(x, ws, zi);
  k_scan<<<dim3(NPAIR * NGH), dim3(256), 0, stream>>>(ws, b_h);
  k_hidden<<<dim3(512, 8), dim3(256), 0, stream>>>(ws, b_h, hid);
  k_out<<<dim3(512), dim3(512), 0, stream>>>(ws, hid, b_out, out);
}